// Round 2
// baseline (79.120 us; speedup 1.0000x reference)
//
#include <hip/hip_runtime.h>

// Batched MHA [B=16,H=16,S=256,D=32]; fp16 ref staged as fp32 in/out.
// v4b: P stays in registers. K*Q^T C-layout -> PV A-fragment regrouping done
// with v_permlane32_swap_b32 + v_permlane16_swap_b32 (inline asm; bit-swap
// decomposition of the fixed quad/reg permutation). No Pb LDS buffer:
// LDS 70KB -> 36.5KB -> 4 blocks/CU (16 waves/CU, was 8). Grid 1024 blocks,
// 1 q-tile per wave; 4 blocks of a head land on the same XCD (L2 reuse).

typedef _Float16 f16;
typedef f16 f16x2 __attribute__((ext_vector_type(2)));
typedef f16 f16x4 __attribute__((ext_vector_type(4)));
typedef f16 f16x8 __attribute__((ext_vector_type(8)));
typedef float f32x4 __attribute__((ext_vector_type(4)));
typedef f16x8 f16x8_u __attribute__((may_alias));
typedef f16x4 f16x4_u __attribute__((may_alias));
typedef f32x4 f32x4_u __attribute__((may_alias));

#define SEQ 256
#define HD 32
#define KP 40     // Ks row pitch (halves): 80 B -> conflict-free b128 reads
#define SP 264    // Vt row pitch (halves): 528 B -> conflict-free b128 reads

static __device__ __forceinline__ unsigned pack2(float a, float b) {
    f16x2 h; h[0] = (f16)a; h[1] = (f16)b;    // RNE casts (match ref numerics)
    return __builtin_bit_cast(unsigned, h);
}

__global__ __launch_bounds__(256, 4)
void attn_kernel(const float* __restrict__ Q, const float* __restrict__ K,
                 const float* __restrict__ V, float* __restrict__ O)
{
    __shared__ __align__(16) f16 Ks[SEQ][KP];      // K row-major fp16 (20.0 KB)
    __shared__ __align__(16) f16 Vt[HD][SP];       // V transposed    (16.5 KB)

    const int tid  = threadIdx.x;
    const int wave = tid >> 6;
    const int lane = tid & 63;
    const int l15  = lane & 15;
    const int quad = lane >> 4;

    const int slice = blockIdx.x & 255;    // 4 parts of a slice -> same XCD (stride 256)
    const int part  = blockIdx.x >> 8;     // 0..3

    const size_t base = (size_t)slice * (SEQ * HD);
    const float* q = Q + base;
    const float* k = K + base;
    const float* v = V + base;
    float*       o = O + base;

    // ---- stage K (row-major) and V (transposed) into LDS as fp16 ----
    #pragma unroll
    for (int it = 0; it < 8; ++it) {
        int vec = tid + it * 256;
        int r = vec >> 3;                  // row 0..255
        int c = (vec & 7) << 2;            // col 0,4,...,28
        f32x4 kv = *(const f32x4_u*)(k + r * HD + c);
        f32x4 vv = *(const f32x4_u*)(v + r * HD + c);
        f16x4 kh;
        #pragma unroll
        for (int j = 0; j < 4; ++j) kh[j] = (f16)kv[j];
        *(f16x4_u*)(&Ks[r][c]) = kh;
        #pragma unroll
        for (int j = 0; j < 4; ++j) Vt[c + j][r] = (f16)vv[j];
    }
    __syncthreads();

    // exp(s/scale) = exp2(s * C), C = log2(e)/float16(sqrt(32))
    const float C_EXP = 1.44269504088896f / 5.65625f;

    const int qt = part * 4 + wave;        // q-tile 0..15, one per wave

    // Q fragment (B-operand of K*Q^T): Q[qt*16+l15][quad*8..+8], fp32->fp16
    const float* qp = q + (qt * 16 + l15) * HD + quad * 8;
    f32x4 a = *(const f32x4_u*)(qp);
    f32x4 b = *(const f32x4_u*)(qp + 4);
    f16x8 qa;
    #pragma unroll
    for (int j = 0; j < 4; ++j) { qa[j] = (f16)a[j]; qa[4 + j] = (f16)b[j]; }

    // ---- S^T + exp, P kept in registers in PV A-fragment layout ----
    // C-layout of K*Q^T tile kt: lane(l15,quad) holds S[q=l15][k=kt*16+quad*4+r].
    // PV A-fragment needs lane(l15,quad) to hold P[q=l15][k=c*32+quad*8+j], j=0..7.
    // Per 32-k block, fp16-pair index p (p3..p0): src lane b5=p2, b4=p1,
    // reg=(p3,p0); dst lane b5=p3, b4=p2, reg=(p1,p0). 3-cycle (reg1,b5,b4):
    //   step1 swap reg1<->b5: v_permlane32_swap (d0,d2), (d1,d3)
    //   step2 swap reg1<->b4: v_permlane16_swap on the same pairs
    float sum = 0.f;
    unsigned pw[8][4];                     // 32 VGPRs of packed fp16 P
    #pragma unroll
    for (int c = 0; c < 8; ++c) {
        f16x8 kf0 = *(const f16x8_u*)(&Ks[(c * 2 + 0) * 16 + l15][quad * 8]);
        f16x8 kf1 = *(const f16x8_u*)(&Ks[(c * 2 + 1) * 16 + l15][quad * 8]);
        f32x4 z = {0.f, 0.f, 0.f, 0.f};
        f32x4 s0 = __builtin_amdgcn_mfma_f32_16x16x32_f16(kf0, qa, z, 0, 0, 0);
        f32x4 s1 = __builtin_amdgcn_mfma_f32_16x16x32_f16(kf1, qa, z, 0, 0, 0);
        float e[8];
        #pragma unroll
        for (int r = 0; r < 4; ++r) e[r]     = __builtin_amdgcn_exp2f(s0[r] * C_EXP);
        #pragma unroll
        for (int r = 0; r < 4; ++r) e[4 + r] = __builtin_amdgcn_exp2f(s1[r] * C_EXP);
        #pragma unroll
        for (int r = 0; r < 8; ++r) sum += e[r];   // unnormalized, <=~330: fp16-safe
        unsigned d0 = pack2(e[0], e[1]);   // p3=0,p0=0  (k = quad*4+{0,1}, even kt)
        unsigned d1 = pack2(e[2], e[3]);   // p3=0,p0=1
        unsigned d2 = pack2(e[4], e[5]);   // p3=1,p0=0  (odd kt)
        unsigned d3 = pack2(e[6], e[7]);   // p3=1,p0=1
        asm("v_permlane32_swap_b32 %0, %1" : "+v"(d0), "+v"(d2));
        asm("v_permlane32_swap_b32 %0, %1" : "+v"(d1), "+v"(d3));
        asm("v_permlane16_swap_b32 %0, %1" : "+v"(d0), "+v"(d2));
        asm("v_permlane16_swap_b32 %0, %1" : "+v"(d1), "+v"(d3));
        pw[c][0] = d0;                     // w0: k = quad*8 + {0,1}
        pw[c][1] = d1;                     // w1: k = quad*8 + {2,3}
        pw[c][2] = d2;                     // w2: k = quad*8 + {4,5}
        pw[c][3] = d3;                     // w3: k = quad*8 + {6,7}
    }
    // combine quads (same l15 = same q-row): full row sum
    sum += __shfl_xor(sum, 16);
    sum += __shfl_xor(sum, 32);
    const float rs = 1.0f / sum;           // per q = l15

    // ---- PV: O[16x32] = P[16x256] @ V[256x32], V B-frags read from LDS ----
    f32x4 o0 = {0.f, 0.f, 0.f, 0.f};
    f32x4 o1 = {0.f, 0.f, 0.f, 0.f};
    #pragma unroll
    for (int c = 0; c < 8; ++c) {
        union { unsigned u[4]; f16x8 v; } pu;
        pu.u[0] = pw[c][0]; pu.u[1] = pw[c][1];
        pu.u[2] = pw[c][2]; pu.u[3] = pw[c][3];
        f16x8 pa  = pu.v;
        f16x8 vb0 = *(const f16x8_u*)(&Vt[l15][c * 32 + quad * 8]);
        f16x8 vb1 = *(const f16x8_u*)(&Vt[16 + l15][c * 32 + quad * 8]);
        o0 = __builtin_amdgcn_mfma_f32_16x16x32_f16(pa, vb0, o0, 0, 0, 0);
        o1 = __builtin_amdgcn_mfma_f32_16x16x32_f16(pa, vb1, o1, 0, 0, 0);
    }

    // ---- epilogue: rows of O are q=quad*4+r4; fetch that row's 1/sum ----
    #pragma unroll
    for (int r4 = 0; r4 < 4; ++r4) {
        const float rsr = __shfl(rs, quad * 4 + r4);   // lane with l15==row
        const int row = qt * 16 + quad * 4 + r4;
        o[row * HD + l15]      = (float)(f16)(o0[r4] * rsr);
        o[row * HD + 16 + l15] = (float)(f16)(o1[r4] * rsr);
    }
}

extern "C" void kernel_launch(void* const* d_in, const int* in_sizes, int n_in,
                              void* d_out, int out_size, void* d_ws, size_t ws_size,
                              hipStream_t stream) {
    const float* q = (const float*)d_in[0];
    const float* k = (const float*)d_in[1];
    const float* v = (const float*)d_in[2];
    float* o = (float*)d_out;
    const int bh = in_sizes[0] / (SEQ * HD);   // 256 head-slices
    attn_kernel<<<bh * 4, 256, 0, stream>>>(q, k, v, o);
}

// Round 4
// 78.077 us; speedup vs baseline: 1.0134x; 1.0134x over previous
//
#include <hip/hip_runtime.h>

// Batched MHA [B=16,H=16,S=256,D=32]; fp16 ref staged as fp32 in/out.
// v6: one block per head-slice, 256 blocks x 512 threads (8 waves, 2 q-tiles
// per wave via qi loop — v3's loop pattern around v4b's verified body).
// K/V staged to LDS ONCE per slice (staging instrs /4 vs v4, reads 74->40MB).
// P stays in registers via v_permlane{32,16}_swap regroup (v4b-verified).

typedef _Float16 f16;
typedef f16 f16x2 __attribute__((ext_vector_type(2)));
typedef f16 f16x4 __attribute__((ext_vector_type(4)));
typedef f16 f16x8 __attribute__((ext_vector_type(8)));
typedef float f32x4 __attribute__((ext_vector_type(4)));
typedef f16x8 f16x8_u __attribute__((may_alias));
typedef f16x4 f16x4_u __attribute__((may_alias));
typedef f32x4 f32x4_u __attribute__((may_alias));

#define SEQ 256
#define HD 32
#define KP 40     // Ks row pitch (halves): 80 B -> conflict-free b128 reads
#define SP 264    // Vt row pitch (halves): 528 B -> conflict-free b128 reads

static __device__ __forceinline__ unsigned pack2(float a, float b) {
    f16x2 h; h[0] = (f16)a; h[1] = (f16)b;    // RNE casts (match ref numerics)
    return __builtin_bit_cast(unsigned, h);
}

__global__ __launch_bounds__(512, 2)
void attn_kernel(const float* __restrict__ Q, const float* __restrict__ K,
                 const float* __restrict__ V, float* __restrict__ O)
{
    __shared__ __align__(16) f16 Ks[SEQ][KP];      // K row-major fp16 (20.0 KB)
    __shared__ __align__(16) f16 Vt[HD][SP];       // V transposed    (16.5 KB)

    const int tid  = threadIdx.x;
    const int wave = tid >> 6;                     // 0..7
    const int lane = tid & 63;
    const int l15  = lane & 15;
    const int quad = lane >> 4;

    const size_t base = (size_t)blockIdx.x * (SEQ * HD);
    const float* q = Q + base;
    const float* k = K + base;
    const float* v = V + base;
    float*       o = O + base;

    // ---- stage K (row-major) and V (transposed) into LDS as fp16, once ----
    #pragma unroll
    for (int it = 0; it < 4; ++it) {
        int vec = tid + it * 512;          // 0..2047
        int r = vec >> 3;                  // row 0..255
        int c = (vec & 7) << 2;            // col 0,4,...,28
        f32x4 kv = *(const f32x4_u*)(k + r * HD + c);
        f32x4 vv = *(const f32x4_u*)(v + r * HD + c);
        f16x4 kh;
        #pragma unroll
        for (int j = 0; j < 4; ++j) kh[j] = (f16)kv[j];
        *(f16x4_u*)(&Ks[r][c]) = kh;
        #pragma unroll
        for (int j = 0; j < 4; ++j) Vt[c + j][r] = (f16)vv[j];
    }
    __syncthreads();

    // exp(s/scale) = exp2(s * C), C = log2(e)/float16(sqrt(32))
    const float C_EXP = 1.44269504088896f / 5.65625f;

    #pragma unroll 1
    for (int qi = 0; qi < 2; ++qi) {
        const int qt = wave * 2 + qi;      // q-tile 0..15

        // Q fragment (B-operand of K*Q^T): Q[qt*16+l15][quad*8..+8], fp32->fp16
        const float* qp = q + (qt * 16 + l15) * HD + quad * 8;
        f32x4 a = *(const f32x4_u*)(qp);
        f32x4 b = *(const f32x4_u*)(qp + 4);
        f16x8 qa;
        #pragma unroll
        for (int j = 0; j < 4; ++j) { qa[j] = (f16)a[j]; qa[4 + j] = (f16)b[j]; }

        // ---- S^T + exp, P kept in registers in PV A-fragment layout ----
        // C-layout of K*Q^T tile kt: lane(l15,quad) holds S[q=l15][k=kt*16+quad*4+r].
        // PV A-fragment needs lane(l15,quad) to hold P[q=l15][k=c*32+quad*8+j].
        // Per 32-k block, fp16-pair index p (p3..p0): src lane b5=p2, b4=p1,
        // reg=(p3,p0); dst lane b5=p3, b4=p2, reg=(p1,p0). 3-cycle (reg1,b5,b4):
        //   step1 swap reg1<->b5: v_permlane32_swap (d0,d2), (d1,d3)
        //   step2 swap reg1<->b4: v_permlane16_swap on the same pairs
        float sum = 0.f;
        unsigned pw[8][4];                 // 32 VGPRs of packed fp16 P
        #pragma unroll
        for (int c = 0; c < 8; ++c) {
            f16x8 kf0 = *(const f16x8_u*)(&Ks[(c * 2 + 0) * 16 + l15][quad * 8]);
            f16x8 kf1 = *(const f16x8_u*)(&Ks[(c * 2 + 1) * 16 + l15][quad * 8]);
            f32x4 z = {0.f, 0.f, 0.f, 0.f};
            f32x4 s0 = __builtin_amdgcn_mfma_f32_16x16x32_f16(kf0, qa, z, 0, 0, 0);
            f32x4 s1 = __builtin_amdgcn_mfma_f32_16x16x32_f16(kf1, qa, z, 0, 0, 0);
            float e[8];
            #pragma unroll
            for (int r = 0; r < 4; ++r) e[r]     = __builtin_amdgcn_exp2f(s0[r] * C_EXP);
            #pragma unroll
            for (int r = 0; r < 4; ++r) e[4 + r] = __builtin_amdgcn_exp2f(s1[r] * C_EXP);
            #pragma unroll
            for (int r = 0; r < 8; ++r) sum += e[r];   // unnormalized, <=~330: fp16-safe
            unsigned d0 = pack2(e[0], e[1]);   // p3=0,p0=0  (k = quad*4+{0,1}, even kt)
            unsigned d1 = pack2(e[2], e[3]);   // p3=0,p0=1
            unsigned d2 = pack2(e[4], e[5]);   // p3=1,p0=0  (odd kt)
            unsigned d3 = pack2(e[6], e[7]);   // p3=1,p0=1
            asm("v_permlane32_swap_b32 %0, %1" : "+v"(d0), "+v"(d2));
            asm("v_permlane32_swap_b32 %0, %1" : "+v"(d1), "+v"(d3));
            asm("v_permlane16_swap_b32 %0, %1" : "+v"(d0), "+v"(d2));
            asm("v_permlane16_swap_b32 %0, %1" : "+v"(d1), "+v"(d3));
            pw[c][0] = d0;                 // w0: k = quad*8 + {0,1}
            pw[c][1] = d1;                 // w1: k = quad*8 + {2,3}
            pw[c][2] = d2;                 // w2: k = quad*8 + {4,5}
            pw[c][3] = d3;                 // w3: k = quad*8 + {6,7}
        }
        // combine quads (same l15 = same q-row): full row sum
        sum += __shfl_xor(sum, 16);
        sum += __shfl_xor(sum, 32);
        const float rs = 1.0f / sum;       // per q = l15

        // ---- PV: O[16x32] = P[16x256] @ V[256x32], V B-frags from LDS ----
        f32x4 o0 = {0.f, 0.f, 0.f, 0.f};
        f32x4 o1 = {0.f, 0.f, 0.f, 0.f};
        #pragma unroll
        for (int c = 0; c < 8; ++c) {
            union { unsigned u[4]; f16x8 v; } pu;
            pu.u[0] = pw[c][0]; pu.u[1] = pw[c][1];
            pu.u[2] = pw[c][2]; pu.u[3] = pw[c][3];
            f16x8 pa  = pu.v;
            f16x8 vb0 = *(const f16x8_u*)(&Vt[l15][c * 32 + quad * 8]);
            f16x8 vb1 = *(const f16x8_u*)(&Vt[16 + l15][c * 32 + quad * 8]);
            o0 = __builtin_amdgcn_mfma_f32_16x16x32_f16(pa, vb0, o0, 0, 0, 0);
            o1 = __builtin_amdgcn_mfma_f32_16x16x32_f16(pa, vb1, o1, 0, 0, 0);
        }

        // ---- epilogue: rows of O are q=quad*4+r4; fetch that row's 1/sum ----
        #pragma unroll
        for (int r4 = 0; r4 < 4; ++r4) {
            const float rsr = __shfl(rs, quad * 4 + r4);   // lane with l15==row
            const int row = qt * 16 + quad * 4 + r4;
            o[row * HD + l15]      = (float)(f16)(o0[r4] * rsr);
            o[row * HD + 16 + l15] = (float)(f16)(o1[r4] * rsr);
        }
    }
}

extern "C" void kernel_launch(void* const* d_in, const int* in_sizes, int n_in,
                              void* d_out, int out_size, void* d_ws, size_t ws_size,
                              hipStream_t stream) {
    const float* q = (const float*)d_in[0];
    const float* k = (const float*)d_in[1];
    const float* v = (const float*)d_in[2];
    float* o = (float*)d_out;
    const int bh = in_sizes[0] / (SEQ * HD);   // 256 head-slices
    attn_kernel<<<bh, 512, 0, stream>>>(q, k, v, o);
}